// Round 1
// 6772.761 us; speedup vs baseline: 1.3773x; 1.3773x over previous
//
#include <hip/hip_runtime.h>

// Problem constants
#define NB    64
#define TT    2048
#define FRAME 512
#define ENC   256
#define HID   128
#define G4    512          // 4*HID
#define ROWS  (NB*TT)      // 131072
#define DEC_OFF 67108864   // decoded elements; out_states follow

__device__ __forceinline__ float sigmoidf_(float x) { return 1.f / (1.f + __expf(-x)); }
__device__ __forceinline__ float tanhf_(float x)    { return 1.f - 2.f / (1.f + __expf(2.f * x)); }

// ---------------------------------------------------------------------------
// K0: zero the reduction accumulators
// ---------------------------------------------------------------------------
__global__ void zero_red(float* p) { p[threadIdx.x] = 0.f; }

// ---------------------------------------------------------------------------
// Tiled fp32 GEMM: C[row][col] = epi( sum_k A[row][k]*B[col][k] + bias[col] )
// Tile 128x128, K-slab 16, 256 threads, 8x8 micro-tile (rows contiguous,
// cols strided by 16 for conflict-free LDS + coalesced C stores).
// AMODE 0: A row-major [row][K]
// AMODE 1: A = y1 layout [n][k][t], row=(n,t)   (K1 encoder)
// EPI 0: plain (+bias if non-null)
// EPI 1: plain + global sum/sumsq atomics into red[0..1]   (K1)
// EPI 2: v = sigmoid(acc+bias[c]) * aux[r][c]              (mask*enc, in-place)
// ---------------------------------------------------------------------------
template<int AMODE, int EPI>
__global__ __launch_bounds__(256, 4)
void gemm_k(const float* __restrict__ A, const float* __restrict__ Bm,
            float* __restrict__ C, const float* __restrict__ bias,
            const float* __restrict__ aux, float* __restrict__ red,
            int K, int ldc)
{
    __shared__ float As[16 * 129];
    __shared__ float Bs[16 * 129];
    const int tid = threadIdx.x;
    const int tx = tid & 15, ty = tid >> 4;
    const int rowbase = blockIdx.x * 128;
    const int colbase = blockIdx.y * 128;
    const int n = rowbase >> 11, t0 = rowbase & 2047;   // AMODE 1 only

    float acc[8][8];
#pragma unroll
    for (int i = 0; i < 8; i++)
#pragma unroll
        for (int j = 0; j < 8; j++) acc[i][j] = 0.f;

    for (int kb = 0; kb < K; kb += 16) {
#pragma unroll
        for (int it = 0; it < 8; it++) {
            const int e = it * 256 + tid;
            if (AMODE == 1) {
                const int r_i = e & 127, k_i = e >> 7;
                As[k_i * 129 + r_i] = A[((size_t)n * FRAME + kb + k_i) * TT + t0 + r_i];
            } else {
                const int k_i = e & 15, r_i = e >> 4;
                As[k_i * 129 + r_i] = A[(size_t)(rowbase + r_i) * K + kb + k_i];
            }
            const int k_i = e & 15, c_i = e >> 4;
            Bs[k_i * 129 + c_i] = Bm[(size_t)(colbase + c_i) * K + kb + k_i];
        }
        __syncthreads();
#pragma unroll
        for (int kk = 0; kk < 16; kk++) {
            float a[8], b[8];
#pragma unroll
            for (int i = 0; i < 8; i++) a[i] = As[kk * 129 + ty * 8 + i];
#pragma unroll
            for (int j = 0; j < 8; j++) b[j] = Bs[kk * 129 + tx + 16 * j];
#pragma unroll
            for (int i = 0; i < 8; i++)
#pragma unroll
                for (int j = 0; j < 8; j++) acc[i][j] = fmaf(a[i], b[j], acc[i][j]);
        }
        __syncthreads();
    }

    float s = 0.f, ss = 0.f;
#pragma unroll
    for (int i = 0; i < 8; i++) {
        const int r = rowbase + ty * 8 + i;
#pragma unroll
        for (int j = 0; j < 8; j++) {
            const int cix = colbase + tx + 16 * j;
            float v = acc[i][j];
            if (EPI == 0) { if (bias) v += bias[cix]; }
            else if (EPI == 2) {
                v = sigmoidf_(v + bias[cix]);
                v *= aux[(size_t)r * ldc + cix];
            }
            C[(size_t)r * ldc + cix] = v;
            if (EPI == 1) { s += v; ss += v * v; }
        }
    }
    if (EPI == 1) {
        __syncthreads();
        As[tid] = s; As[256 + tid] = ss;
        __syncthreads();
        for (int st = 128; st > 0; st >>= 1) {
            if (tid < st) { As[tid] += As[tid + st]; As[256 + tid] += As[256 + tid + st]; }
            __syncthreads();
        }
        if (tid == 0) { atomicAdd(&red[0], As[0]); atomicAdd(&red[1], As[256]); }
    }
}

// ---------------------------------------------------------------------------
// K2: finalize mean/var; fold LayerNorm into Wih1 -> Wf, bias1f; bias2f.
// grid 512 (one block per gate row), 256 threads (one per input channel).
// ---------------------------------------------------------------------------
__global__ __launch_bounds__(256)
void fold_norm(const float* __restrict__ red, const float* __restrict__ Wih1,
               const float* __restrict__ gamma, const float* __restrict__ beta,
               const float* __restrict__ bih1, const float* __restrict__ bhh1,
               const float* __restrict__ bih2, const float* __restrict__ bhh2,
               float* __restrict__ Wf, float* __restrict__ b1f, float* __restrict__ b2f)
{
    const int j = blockIdx.x;      // gate row 0..511
    const int c = threadIdx.x;     // channel 0..255
    const float M = (float)ROWS * (float)ENC;   // 33554432
    const float mean = red[0] / M;
    const float var  = red[1] / M - mean * mean;
    const float rstd = rsqrtf(var + 1e-7f);
    const float scale = gamma[c] * rstd;
    const float shift = beta[c] - mean * scale;
    const float w = Wih1[j * ENC + c];
    Wf[j * ENC + c] = w * scale;
    __shared__ float rbuf[256];
    rbuf[c] = w * shift;
    __syncthreads();
    for (int s = 128; s > 0; s >>= 1) {
        if (c < s) rbuf[c] += rbuf[c + s];
        __syncthreads();
    }
    if (c == 0) {
        b1f[j] = bih1[j] + bhh1[j] + rbuf[0];
        b2f[j] = bih2[j] + bhh2[j];
    }
}

// ---------------------------------------------------------------------------
// Sequential LSTM pass. One block per batch sample (64 blocks, 512 threads).
//
// Lane mapping: wave w owns hidden units j = 16w .. 16w+15.
//   lane = (g<<4) | jj  within the wave: gate g (0..3 = i,f,g,o), unit jj.
// Each thread computes one gate-row dot (Whh row g*HID+j, 128 FMAs, weights
// in VGPRs — __launch_bounds__(512,2) grants 256 VGPRs), applies its own
// activation branch-free (v = 1 - k/(1+exp(k*x)); k=1 sigmoid, k=2 tanh),
// then the 4 gates of unit j are gathered with 4 in-wave __shfl's.
// c is replicated across the 4 gate lanes of each unit (kept in-register).
// h is double-buffered in LDS (hA/hB) -> ONE barrier per step:
//   step t reads hR, writes hW; barrier at step end covers RAW for t+1
//   and WAR (t's reads of hR precede the barrier, t+1's writes hit hR).
// No G[] LDS round-trip, no idle-wave gate phase, no second barrier.
// ---------------------------------------------------------------------------
__global__ __launch_bounds__(512, 2)
void lstm_seq(const float* __restrict__ xg, const float* __restrict__ Whh,
              const float* __restrict__ states_in, int h_idx, int c_idx,
              float* __restrict__ xout, float* __restrict__ out_states)
{
    const int nblk = blockIdx.x;
    const int tid  = threadIdx.x;
    const int lane = tid & 63;
    const int wv   = tid >> 6;          // wave 0..7
    const int g    = lane >> 4;         // gate 0..3 (i,f,g,o)
    const int jj   = lane & 15;         // unit within wave
    const int j    = wv * 16 + jj;      // hidden unit 0..127
    const int row  = g * HID + j;       // gate row / xg column, 0..511

    __shared__ __align__(16) float hA[HID];
    __shared__ __align__(16) float hB[HID];

    // weight row -> registers (128 VGPRs; fits under the 256-VGPR bound)
    float w[128];
    {
        const float4* wg = (const float4*)(Whh + (size_t)row * HID);
#pragma unroll
        for (int k4 = 0; k4 < 32; k4++) {
            float4 v = wg[k4];
            w[k4 * 4 + 0] = v.x; w[k4 * 4 + 1] = v.y;
            w[k4 * 4 + 2] = v.z; w[k4 * 4 + 3] = v.w;
        }
    }

    // c replicated across the 4 gate lanes of unit j
    float c = states_in[c_idx * (NB * HID) + nblk * HID + j];
    if (g == 0) hA[j] = states_in[h_idx * (NB * HID) + nblk * HID + j];
    __syncthreads();

    // activation constant: v = 1 - ak/(1 + exp(ak*x)); ak=1 sigmoid, ak=2 tanh
    const float ak = (g == 2) ? 2.f : 1.f;

    const float* xgn = xg + (size_t)nblk * TT * G4 + row;   // stride G4 per t
    float* xon = xout + (size_t)nblk * TT * HID + j;        // g==0 lanes store

    float xg_cur = xgn[0];
    float h = 0.f;

    // one LSTM step: dot(w, h_rd) -> activation -> shfl-gather -> c,h update
    auto step = [&](const float* __restrict__ hrd, float* __restrict__ hwr,
                    int t, float xg_nxt) {
        float a0 = 0.f, a1 = 0.f, a2 = 0.f, a3 = 0.f;
        const float4* h4 = (const float4*)hrd;
#pragma unroll
        for (int k4 = 0; k4 < 32; k4++) {
            float4 hv = h4[k4];
            a0 = fmaf(w[k4 * 4 + 0], hv.x, a0);
            a1 = fmaf(w[k4 * 4 + 1], hv.y, a1);
            a2 = fmaf(w[k4 * 4 + 2], hv.z, a2);
            a3 = fmaf(w[k4 * 4 + 3], hv.w, a3);
        }
        const float pre = xg_cur + ((a0 + a1) + (a2 + a3));
        const float v = 1.f - ak / (1.f + __expf(ak * pre));
        // gather the 4 activated gates of unit j (lanes jj, jj+16, jj+32, jj+48)
        const float iv = __shfl(v, jj);
        const float fv = __shfl(v, jj + 16);
        const float gv = __shfl(v, jj + 32);
        const float ov = __shfl(v, jj + 48);
        c = fmaf(fv, c, iv * gv);
        const float th = 1.f - 2.f / (1.f + __expf(2.f * c));
        h = ov * th;
        if (g == 0) { hwr[j] = h; xon[(size_t)t * HID] = h; }
        xg_cur = xg_nxt;
        __syncthreads();
    };

    for (int t = 0; t < TT; t += 2) {
        // even step: read hA, write hB. t+1 <= 2047 always valid.
        {
            const float xg_next = xgn[(size_t)(t + 1) * G4];
            step(hA, hB, t, xg_next);
        }
        // odd step: read hB, write hA. guard t+2 prefetch.
        {
            const float xg_next = (t + 2 < TT) ? xgn[(size_t)(t + 2) * G4] : 0.f;
            step(hB, hA, t + 1, xg_next);
        }
    }

    if (g == 0) {
        out_states[h_idx * (NB * HID) + nblk * HID + j] = h;
        out_states[c_idx * (NB * HID) + nblk * HID + j] = c;
    }
}

// ---------------------------------------------------------------------------
// K6: transpose [N][T][512] -> [N][512][T] (final decoded layout)
// ---------------------------------------------------------------------------
__global__ __launch_bounds__(256)
void transpose_nt(const float* __restrict__ src, float* __restrict__ dst)
{
    __shared__ float tile[32][33];
    const int n  = blockIdx.z;
    const int t0 = blockIdx.x * 32;
    const int o0 = blockIdx.y * 32;
    const int lx = threadIdx.x, ly = threadIdx.y;   // 32 x 8
    for (int r = ly; r < 32; r += 8)
        tile[r][lx] = src[((size_t)n * TT + t0 + r) * FRAME + o0 + lx];
    __syncthreads();
    for (int r = ly; r < 32; r += 8)
        dst[((size_t)n * FRAME + o0 + r) * TT + t0 + lx] = tile[lx][r];
}

// ---------------------------------------------------------------------------
extern "C" void kernel_launch(void* const* d_in, const int* in_sizes, int n_in,
                              void* d_out, int out_size, void* d_ws, size_t ws_size,
                              hipStream_t stream)
{
    const float* y1     = (const float*)d_in[0];
    const float* states = (const float*)d_in[1];
    const float* W_enc  = (const float*)d_in[2];
    const float* gamma  = (const float*)d_in[3];
    const float* beta   = (const float*)d_in[4];
    const float* Wih1   = (const float*)d_in[5];
    const float* Whh1   = (const float*)d_in[6];
    const float* bih1   = (const float*)d_in[7];
    const float* bhh1   = (const float*)d_in[8];
    const float* Wih2   = (const float*)d_in[9];
    const float* Whh2   = (const float*)d_in[10];
    const float* bih2   = (const float*)d_in[11];
    const float* bhh2   = (const float*)d_in[12];
    const float* Wd     = (const float*)d_in[13];
    const float* bd     = (const float*)d_in[14];
    const float* W_dec  = (const float*)d_in[15];

    float* out = (float*)d_out;
    float* out_states = out + DEC_OFF;

    // workspace layout (floats)
    float* ws    = (float*)d_ws;
    float* encf  = ws;                                  // [N][T][256]  33,554,432
    float* xg    = encf + (size_t)ROWS * ENC;           // [N][T][512]  67,108,864
    float* xbuf  = xg + (size_t)ROWS * G4;              // [N][T][128]  16,777,216
    float* Wf    = xbuf + (size_t)ROWS * HID;           // [512][256]
    float* b1f   = Wf + G4 * ENC;                       // [512]
    float* b2f   = b1f + G4;                            // [512]
    float* red   = b2f + G4;                            // [2]
    const size_t needed = (size_t)(red + 2 - ws) * sizeof(float);
    if (ws_size < needed) return;   // insufficient scratch: fail loudly

    const dim3 blk(256);

    // K0: zero reduction scalars
    zero_red<<<1, 2, 0, stream>>>(red);

    // K1: encf = y1^T @ W_enc^T  (per n), + global sum/sumsq
    gemm_k<1, 1><<<dim3(ROWS / 128, ENC / 128), blk, 0, stream>>>(
        y1, W_enc, encf, nullptr, nullptr, red, FRAME, ENC);

    // K2: fold LN into Wih1
    fold_norm<<<G4, 256, 0, stream>>>(red, Wih1, gamma, beta, bih1, bhh1,
                                      bih2, bhh2, Wf, b1f, b2f);

    // K3: xg1 = encf @ Wf^T + b1f
    gemm_k<0, 0><<<dim3(ROWS / 128, G4 / 128), blk, 0, stream>>>(
        encf, Wf, xg, b1f, nullptr, nullptr, ENC, G4);

    // K4a: LSTM1 sequential -> xbuf (=x1), states h1,c1
    lstm_seq<<<NB, 512, 0, stream>>>(xg, Whh1, states, 0, 1, xbuf, out_states);

    // K4b: xg2 = x1 @ Wih2^T + b2f  (overwrites xg)
    gemm_k<0, 0><<<dim3(ROWS / 128, G4 / 128), blk, 0, stream>>>(
        xbuf, Wih2, xg, b2f, nullptr, nullptr, HID, G4);

    // K4c: LSTM2 sequential -> xbuf (=x2), states h2,c2
    lstm_seq<<<NB, 512, 0, stream>>>(xg, Whh2, states, 2, 3, xbuf, out_states);

    // K5a: est = sigmoid(x2 @ Wd^T + bd) * encf   (in-place into encf)
    gemm_k<0, 2><<<dim3(ROWS / 128, ENC / 128), blk, 0, stream>>>(
        xbuf, Wd, encf, bd, encf, nullptr, HID, ENC);

    // K5b: Ctmp = est @ W_dec^T   (row-major [N][T][512] into xg)
    gemm_k<0, 0><<<dim3(ROWS / 128, G4 / 128), blk, 0, stream>>>(
        encf, W_dec, xg, nullptr, nullptr, nullptr, ENC, G4);

    // K6: transpose -> decoded [N][512][T]
    transpose_nt<<<dim3(TT / 32, FRAME / 32, NB), dim3(32, 8), 0, stream>>>(xg, out);
}